// Round 12
// baseline (375.796 us; speedup 1.0000x reference)
//
#include <hip/hip_runtime.h>
#include <hip/hip_bf16.h>

typedef __attribute__((ext_vector_type(8))) int   i32x8;
typedef __attribute__((ext_vector_type(4))) int   i32x4;
typedef __attribute__((ext_vector_type(4))) float f32x4;

#define SDIM 49
#define NDIM 1024
#define CDIM 384
#define DDIM 512
#define DMC  64
#define NSTEP 4             // 512 / 128
#define SCALE (1.0f/(SDIM*NDIM))
#define SLOT 65536          // A(keys) 256x128B=32KB + B(q) 32KB per K-step; 2 slots = 128KB

__device__ __forceinline__ void gload16(const void* g, void* l) {
    __builtin_amdgcn_global_load_lds((const __attribute__((address_space(1))) void*)g,
                                     (__attribute__((address_space(3))) void*)l, 16, 0, 0);
}

__device__ __forceinline__ unsigned char f2fp8(float v) {
    return (unsigned char)(__builtin_amdgcn_cvt_pk_fp8_f32(v, v, 0, false) & 0xff);
}

// ---------------------------------------------------------------------------
// pack (fp8 e4m3) + passthrough copy fused from registers (R10 form).
// dst rows: [512] fp8 = x(384) | m(64) | c(64).
// ---------------------------------------------------------------------------
__global__ __launch_bounds__(512) void pack_copy_kernel(
    const float* __restrict__ xloc, const float* __restrict__ mv,
    const float* __restrict__ cv,   unsigned char* __restrict__ dst,
    float* __restrict__ cpy)
{
    const int j = blockIdx.x;
    const int d = threadIdx.x;
    float vals[SDIM];
    if (d < CDIM) {
        const float* p = xloc + ((size_t)j * CDIM + d) * SDIM;
        #pragma unroll
        for (int s = 0; s < SDIM; ++s) vals[s] = p[s];
        float* dcp = cpy + ((size_t)j * CDIM + d) * SDIM;
        #pragma unroll
        for (int s = 0; s < SDIM; ++s) dcp[s] = vals[s];
    } else if (d < CDIM + DMC) {
        float v = mv[j * DMC + (d - CDIM)];
        #pragma unroll
        for (int s = 0; s < SDIM; ++s) vals[s] = v;
    } else {
        float v = cv[j * DMC + (d - CDIM - DMC)];
        #pragma unroll
        for (int s = 0; s < SDIM; ++s) vals[s] = v;
    }
    #pragma unroll
    for (int s = 0; s < SDIM; ++s)
        dst[((size_t)s * NDIM + j) * DDIM + d] = f2fp8(vals[s]);
}

__global__ void fpack_kernel(const float* __restrict__ f,
                             unsigned char* __restrict__ dst, int n)
{
    int i = blockIdx.x * blockDim.x + threadIdx.x;
    if (i < n) dst[i] = f2fp8(f[i]);
}

// ---------------------------------------------------------------------------
// PERSISTENT fused GEMM + partial-LSE, R10 minimal-sync schedule, fp8 MX K=128.
// grid = 256 blocks of 512 (8 waves = 2 wk x 4 wq); block (xcd=bid&7, jj)
// owns tiles g = 196*xcd + jj + 32k.  Tile g: s=g>>5, kb=(g>>3)&3, qb=g&7.
// Tile: 256 keys x 256 q, BK=128 fp8 (4 K-steps); wave tile 128 keys x 64 q.
// MFMA: mfma_scale_f32_16x16x128_f8f6f4, fp8/fp8, scales=127 (x1.0).
// A/B frag: lane row=l15, 32 contiguous K bytes at l4*32 (2x b128 reads);
// any k-permutation cancels (same map on A and B).  C/D (shape-determined,
// validated R6-R10): col=lane&15, row=(lane>>4)*4+reg -> acc[a=0..7][b=0..3].
// LDS slot: A rows [256][128B] @0, B rows [256][128B] @32K; content[row][col]
// = G[row][kstep*128 + (col ^ ((row&7)<<4))]; linear LDS dest + pre-swizzled
// global source (0 bank conflicts; 2-way on frag reads = free).
// K-step = ONE __syncthreads (vmcnt0+lgkm0 drain = slot handoff), stage8(t+1)
// pinned first, reads+MFMAs compiler-scheduled.  t=3 stages next tile's step 0.
// ---------------------------------------------------------------------------
__global__ __launch_bounds__(512, 2) void loss_kernel(
    const unsigned char* __restrict__ Fm,   // [N,512] fp8
    const unsigned char* __restrict__ Km,   // [S,N,512] fp8 keys
    const unsigned char* __restrict__ Qm,   // [S,N,512] fp8 queries (pred2)
    float2* __restrict__ part,              // [S*2048][8]
    float* __restrict__ out)
{
    extern __shared__ __attribute__((aligned(16))) char sm[];   // 2*SLOT

    const int bid = blockIdx.x;
    const int xcd = bid & 7;
    const int jj  = bid >> 3;
    const int g0  = 196 * xcd;
    const int gend = g0 + 196;

    const int tid  = threadIdx.x;
    const int lane = tid & 63;
    const int w    = tid >> 6;
    const int l15  = lane & 15;
    const int l4   = lane >> 4;   // 0..3
    const int wk   = w >> 2;      // 0..1 key half
    const int wq   = w & 3;       // 0..3 q quarter

    // staging: thread covers rows c*64 + (tid>>3), 16B slot (tid&7)*16;
    // pre-swizzled source col = col ^ ((row&7)<<4)
    const int trow = tid >> 3;
    const int scol = (((tid & 7) ^ ((tid >> 3) & 7)) << 4);

    const unsigned xo   = (unsigned)((l15 & 7) << 4);
    const unsigned arow = (unsigned)((wk * 128 + l15) * 128);
    const unsigned brow = 32768u + (unsigned)((wq * 64 + l15) * 128);
    const unsigned ko4  = (unsigned)(l4 * 32);

    auto APtr = [&](int g) -> const unsigned char* {
        const int s = g >> 5, kb = (g >> 3) & 3;
        return Km + ((size_t)s * NDIM + (size_t)kb * 256) * DDIM;
    };
    auto BPtr = [&](int g) -> const unsigned char* {
        const int s = g >> 5, qb = g & 7;
        return (qb < 4)
            ? (Fm + (size_t)qb * 256 * DDIM)
            : (Qm + ((size_t)s * NDIM + (size_t)(qb - 4) * 256) * DDIM);
    };
    auto stage8 = [&](const unsigned char* A, const unsigned char* B, int ko, char* slot) {
        #pragma unroll
        for (int c = 0; c < 4; ++c) {
            gload16(A + (size_t)(c * 64 + trow) * DDIM + ko + scol,
                    slot + c * 8192 + tid * 16);
            gload16(B + (size_t)(c * 64 + trow) * DDIM + ko + scol,
                    slot + 32768 + c * 8192 + tid * 16);
        }
    };

    f32x4 acc[8][4];
    i32x8 afr[4], bfr[4];

    #define LOADFRAG(D, BASE) do {                                            \
        i32x4 lo_ = *(const i32x4*)(sb_ + (BASE) + (ko4 ^ xo));               \
        i32x4 hi_ = *(const i32x4*)(sb_ + (BASE) + ((ko4 + 16u) ^ xo));       \
        D[0]=lo_[0]; D[1]=lo_[1]; D[2]=lo_[2]; D[3]=lo_[3];                   \
        D[4]=hi_[0]; D[5]=hi_[1]; D[6]=hi_[2]; D[7]=hi_[3];                   \
    } while (0)

    #define MFMA16(AH) do {                                                   \
        _Pragma("unroll")                                                     \
        for (int a = 0; a < 4; ++a)                                           \
            _Pragma("unroll")                                                 \
            for (int b = 0; b < 4; ++b)                                       \
                acc[(AH)*4 + a][b] =                                          \
                    __builtin_amdgcn_mfma_scale_f32_16x16x128_f8f6f4(         \
                        afr[a], bfr[b], acc[(AH)*4 + a][b],                   \
                        0, 0, 0, 127, 0, 127);                                \
    } while (0)

    // prologue: first tile's step 0 into slot 0
    stage8(APtr(g0 + jj), BPtr(g0 + jj), 0, sm);

    for (int g = g0 + jj; g < gend; g += 32) {
        const unsigned char* Ag = APtr(g);
        const unsigned char* Bg = BPtr(g);
        const bool hasNext = (g + 32) < gend;
        const unsigned char* An = hasNext ? APtr(g + 32) : Ag;
        const unsigned char* Bn = hasNext ? BPtr(g + 32) : Bg;

        #pragma unroll
        for (int a = 0; a < 8; ++a)
            #pragma unroll
            for (int b = 0; b < 4; ++b) acc[a][b] = f32x4{0.f, 0.f, 0.f, 0.f};

        #pragma unroll
        for (int t = 0; t < NSTEP; ++t) {
            const char* sb_ = sm + (size_t)(t & 1) * SLOT;
            char* ns_ = sm + (size_t)((t + 1) & 1) * SLOT;

            __syncthreads();   // vmcnt0+lgkm0 drain = slot handoff (R10)

            if ((t < NSTEP - 1) || hasNext) {
                const unsigned char* sA = (t < NSTEP - 1) ? Ag : An;
                const unsigned char* sB = (t < NSTEP - 1) ? Bg : Bn;
                stage8(sA, sB, (t < NSTEP - 1) ? (t + 1) * 128 : 0, ns_);
            }
            __builtin_amdgcn_sched_barrier(0);   // pin stage-issue first

            // half 1: A frags 0..3 + all B frags, 16 MFMA
            #pragma unroll
            for (int a = 0; a < 4; ++a) LOADFRAG(afr[a], arow + a * 2048u);
            #pragma unroll
            for (int b = 0; b < 4; ++b) LOADFRAG(bfr[b], brow + b * 2048u);
            __builtin_amdgcn_s_setprio(1); MFMA16(0); __builtin_amdgcn_s_setprio(0);
            // half 2: A frags 4..7 (reuse regs), 16 MFMA
            #pragma unroll
            for (int a = 0; a < 4; ++a) LOADFRAG(afr[a], arow + (4 + a) * 2048u);
            __builtin_amdgcn_s_setprio(1); MFMA16(1); __builtin_amdgcn_s_setprio(0);
        }

        // ---- epilogue (overlaps next tile's in-flight step-0 loads)
        const int s  = g >> 5;
        const int kb = (g >> 3) & 3;
        const int qb = g & 7;

        float q_m[4], q_s[4];
        #pragma unroll
        for (int b = 0; b < 4; ++b) {
            float m = -3.0e38f;
            #pragma unroll
            for (int a = 0; a < 8; ++a)
                #pragma unroll
                for (int r = 0; r < 4; ++r) m = fmaxf(m, acc[a][b][r]);
            float ss = 0.0f;
            #pragma unroll
            for (int a = 0; a < 8; ++a)
                #pragma unroll
                for (int r = 0; r < 4; ++r) ss += __expf(acc[a][b][r] - m);
            #pragma unroll
            for (int off = 16; off <= 32; off <<= 1) {
                float mo = __shfl_xor(m, off, 64);
                float so = __shfl_xor(ss, off, 64);
                float nm = fmaxf(m, mo);
                ss = ss * __expf(m - nm) + so * __expf(mo - nm);
                m = nm;
            }
            q_m[b] = m; q_s[b] = ss;
        }
        if (lane < 16) {
            const size_t rowb = (size_t)s * 2048 + (size_t)qb * 256 + wq * 64 + lane;
            #pragma unroll
            for (int b = 0; b < 4; ++b)
                part[(rowb + b * 16) * 8 + kb * 2 + wk] = make_float2(q_m[b], q_s[b]);
        }

        // diag: block cond kb == qb&3, wave cond wq>>1 == wk; a = (wq&1)*4+b;
        // lane cond l15>>2 == l4, reg r = lane&3 (compile-time indexed).
        if (kb == (qb & 3) && (wq >> 1) == wk) {
            float d = 0.0f;
            const bool lok = (((lane >> 2) & 3) == l4);
            if (wq & 1) {
                #pragma unroll
                for (int b = 0; b < 4; ++b)
                    #pragma unroll
                    for (int r = 0; r < 4; ++r)
                        if (lok && r == (lane & 3)) d += acc[4 + b][b][r];
            } else {
                #pragma unroll
                for (int b = 0; b < 4; ++b)
                    #pragma unroll
                    for (int r = 0; r < 4; ++r)
                        if (lok && r == (lane & 3)) d += acc[b][b][r];
            }
            #pragma unroll
            for (int off = 1; off < 64; off <<= 1) d += __shfl_xor(d, off, 64);
            if (lane == 0) atomicAdd(out, -d * SCALE);
        }
    }
    #undef LOADFRAG
    #undef MFMA16
}

// merge the 8 per-(kb,wk) partials of each row -> lse, accumulate loss
__global__ __launch_bounds__(256) void reduce_kernel(
    const float2* __restrict__ part, float* __restrict__ out)
{
    const int row = blockIdx.x * 256 + threadIdx.x;   // 392*256 = 100352 rows
    const float2* p = part + (size_t)row * 8;
    float m = -3.0e38f;
    float2 q[8];
    #pragma unroll
    for (int i = 0; i < 8; ++i) { q[i] = p[i]; m = fmaxf(m, q[i].x); }
    float ssum = 0.0f;
    #pragma unroll
    for (int i = 0; i < 8; ++i) ssum += q[i].y * __expf(q[i].x - m);
    float v = m + __logf(ssum);
    #pragma unroll
    for (int off = 1; off < 64; off <<= 1) v += __shfl_xor(v, off, 64);
    __shared__ float red[4];
    const int lane = threadIdx.x & 63, w = threadIdx.x >> 6;
    if (lane == 0) red[w] = v;
    __syncthreads();
    if (threadIdx.x == 0)
        atomicAdd(out, (red[0] + red[1] + red[2] + red[3]) * SCALE);
}

extern "C" void kernel_launch(void* const* d_in, const int* in_sizes, int n_in,
                              void* d_out, int out_size, void* d_ws, size_t ws_size,
                              hipStream_t stream)
{
    (void)in_sizes; (void)n_in; (void)out_size; (void)ws_size;
    const float* f  = (const float*)d_in[0];
    const float* x  = (const float*)d_in[1];
    const float* xp = (const float*)d_in[2];
    const float* mt = (const float*)d_in[3];
    const float* mp = (const float*)d_in[4];
    const float* ct = (const float*)d_in[5];
    const float* cp = (const float*)d_in[6];
    float* out = (float*)d_out;

    char* ws = (char*)d_ws;
    const size_t packBytes = (size_t)SDIM * NDIM * DDIM;   // 25.7 MB (fp8)
    unsigned char* Km = (unsigned char*)ws;
    unsigned char* Qm = (unsigned char*)(ws + packBytes);
    unsigned char* Fm = (unsigned char*)(ws + 2 * packBytes);
    float2* part = (float2*)(ws + 2 * packBytes + (size_t)NDIM * DDIM);

    hipMemsetAsync(out, 0, sizeof(float), stream);

    const int sz = NDIM * CDIM * SDIM;
    pack_copy_kernel<<<NDIM, 512, 0, stream>>>(xp, mp, cp, Km, out + 1);
    pack_copy_kernel<<<NDIM, 512, 0, stream>>>(x,  mt, ct, Qm, out + 1 + sz);
    fpack_kernel<<<(NDIM * DDIM + 255) / 256, 256, 0, stream>>>(f, Fm, NDIM * DDIM);

    loss_kernel<<<256, 512, 2 * SLOT, stream>>>(Fm, Km, Qm, part, out);
    reduce_kernel<<<392, 256, 0, stream>>>(part, out);
}

// Round 13
// 221.095 us; speedup vs baseline: 1.6997x; 1.6997x over previous
//
#include <hip/hip_runtime.h>
#include <hip/hip_bf16.h>

typedef __attribute__((ext_vector_type(8))) __bf16 bf16x8;
typedef __attribute__((ext_vector_type(4))) float  f32x4;

#define SDIM 49
#define NDIM 1024
#define CDIM 384
#define DDIM 512
#define DMC  64
#define SCALE (1.0f/(SDIM*NDIM))
#define SLOT 65536   // A(keys) 32KB + B(q) 32KB per K-step slot; 2 slots = 128KB
#define CHUNK 24576  // floats copied per tile: 1568*24576 == 2*1024*384*49

__device__ __forceinline__ void gload16(const void* g, void* l) {
    __builtin_amdgcn_global_load_lds((const __attribute__((address_space(1))) void*)g,
                                     (__attribute__((address_space(3))) void*)l, 16, 0, 0);
}

// ---------------------------------------------------------------------------
// pack only (copy moved into loss kernel): x [N,C,S] + m + c -> bf16 [S,N,512].
// ---------------------------------------------------------------------------
__global__ __launch_bounds__(512) void pack_kernel(
    const float* __restrict__ xloc, const float* __restrict__ mv,
    const float* __restrict__ cv,   __hip_bfloat16* __restrict__ dst)
{
    const int j = blockIdx.x;
    const int d = threadIdx.x;
    float vals[SDIM];
    if (d < CDIM) {
        const float* p = xloc + ((size_t)j * CDIM + d) * SDIM;
        #pragma unroll
        for (int s = 0; s < SDIM; ++s) vals[s] = p[s];
    } else if (d < CDIM + DMC) {
        float v = mv[j * DMC + (d - CDIM)];
        #pragma unroll
        for (int s = 0; s < SDIM; ++s) vals[s] = v;
    } else {
        float v = cv[j * DMC + (d - CDIM - DMC)];
        #pragma unroll
        for (int s = 0; s < SDIM; ++s) vals[s] = v;
    }
    #pragma unroll
    for (int s = 0; s < SDIM; ++s)
        dst[((size_t)s * NDIM + j) * DDIM + d] = __float2bfloat16(vals[s]);
}

// fpack also zero-inits the loss accumulator (replaces the memset dispatch).
__global__ void fpack_kernel(const float* __restrict__ f,
                             __hip_bfloat16* __restrict__ dst, int n,
                             float* __restrict__ out0)
{
    int i = blockIdx.x * blockDim.x + threadIdx.x;
    if (i == 0) out0[0] = 0.0f;
    if (i < n) dst[i] = __float2bfloat16(f[i]);
}

// ---------------------------------------------------------------------------
// PERSISTENT fused GEMM + partial-LSE, MINIMAL-SYNC schedule (R10, validated
// 125.8us / MfmaUtil 36%), + passthrough copy hidden in the epilogue.
// grid = 256 blocks of 512 (8 waves = 2 wk x 4 wq); block (xcd=bid&7, jj)
// owns tiles g = 196*xcd + jj + 32k.  Tile g: s=g>>5, kb=(g>>3)&3, qb=g&7.
// Tile: 256 keys x 256 q, BK=64 (8 K-steps); wave tile 128 keys x 64 q.
// MFMA 16x16x32 bf16: acc[a=0..7][b=0..3] f32x4; C/D col=lane&15,
// row=(lane>>4)*4+reg (validated R6-R10).
// LDS slot: A rows [256][128B] @0, B rows [256][128B] @32K;
// content[row][col] = G[row][kstep*128 + (col ^ ((row&7)<<4))]; linear LDS
// dest + pre-swizzled global source (R4-R10: 0 bank conflicts).
// K-step = ONE __syncthreads (vmcnt0+lgkm0 drain = slot handoff), stage8(t+1)
// pinned first (sched_barrier), reads+MFMAs compiler-scheduled.
// Copy: tile g moves CHUNK floats (g<784: from xp, else from x) to out+1;
// loads issued at epilogue start (latency hidden under LSE math), stores
// after diag, ~500cy before the next tile's vmcnt(0) sync.
// ---------------------------------------------------------------------------
__global__ __launch_bounds__(512, 2) void loss_kernel(
    const __hip_bfloat16* __restrict__ Fm,   // [N,384..512]
    const __hip_bfloat16* __restrict__ Km,   // [S,N,512] keys
    const __hip_bfloat16* __restrict__ Qm,   // [S,N,512] queries (pred2)
    const float* __restrict__ xp,            // copy source 1
    const float* __restrict__ xq,            // copy source 2
    float* __restrict__ outv,                // out+1 (copy dest)
    float2* __restrict__ part,               // [S*2048][8]
    float* __restrict__ out)
{
    extern __shared__ __attribute__((aligned(16))) char sm[];   // 2*SLOT

    const int bid = blockIdx.x;
    const int xcd = bid & 7;
    const int jj  = bid >> 3;
    const int g0  = 196 * xcd;
    const int gend = g0 + 196;

    const int tid  = threadIdx.x;
    const int lane = tid & 63;
    const int w    = tid >> 6;
    const int l15  = lane & 15;
    const int l4   = lane >> 4;   // 0..3
    const int wk   = w >> 2;      // 0..1 key half
    const int wq   = w & 3;       // 0..3 q quarter

    const int trow = tid >> 3;
    const int scol = (((tid & 7) ^ ((tid >> 3) & 7)) << 4);

    const unsigned xo   = (unsigned)((l15 & 7) << 4);
    const unsigned arow = (unsigned)((wk * 128 + l15) * 128);
    const unsigned brow = 32768u + (unsigned)((wq * 64 + l15) * 128);

    auto APtr = [&](int g) -> const char* {
        const int s = g >> 5, kb = (g >> 3) & 3;
        return (const char*)Km + ((size_t)s * NDIM + (size_t)kb * 256) * 1024;
    };
    auto BPtr = [&](int g) -> const char* {
        const int s = g >> 5, qb = g & 7;
        return (qb < 4)
            ? ((const char*)Fm + (size_t)qb * 256 * 1024)
            : ((const char*)Qm + ((size_t)s * NDIM + (size_t)(qb - 4) * 256) * 1024);
    };
    auto stage8 = [&](const char* A, const char* B, int ko, char* slot) {
        #pragma unroll
        for (int c = 0; c < 4; ++c) {
            gload16(A + (size_t)(c * 64 + trow) * 1024 + ko + scol,
                    slot + c * 8192 + tid * 16);
            gload16(B + (size_t)(c * 64 + trow) * 1024 + ko + scol,
                    slot + 32768 + c * 8192 + tid * 16);
        }
    };

    f32x4 acc[8][4];
    bf16x8 afr[8], bfr[4];

    #define READ12(KC) do {                                                   \
        const unsigned co = ((unsigned)((KC) * 64 + l4 * 16)) ^ xo;           \
        _Pragma("unroll")                                                     \
        for (int a = 0; a < 8; ++a)                                           \
            afr[a] = *(const bf16x8*)(sb_ + arow + a * 2048u + co);           \
        _Pragma("unroll")                                                     \
        for (int b = 0; b < 4; ++b)                                           \
            bfr[b] = *(const bf16x8*)(sb_ + brow + b * 2048u + co);           \
    } while (0)

    #define MFMA32() do {                                                     \
        _Pragma("unroll")                                                     \
        for (int a = 0; a < 8; ++a)                                           \
            _Pragma("unroll")                                                 \
            for (int b = 0; b < 4; ++b)                                       \
                acc[a][b] = __builtin_amdgcn_mfma_f32_16x16x32_bf16(          \
                    afr[a], bfr[b], acc[a][b], 0, 0, 0);                      \
    } while (0)

    // prologue: first tile's step 0 into slot 0
    stage8(APtr(g0 + jj), BPtr(g0 + jj), 0, sm);

    for (int g = g0 + jj; g < gend; g += 32) {
        const char* Ag = APtr(g);
        const char* Bg = BPtr(g);
        const bool hasNext = (g + 32) < gend;
        const char* An = hasNext ? APtr(g + 32) : Ag;
        const char* Bn = hasNext ? BPtr(g + 32) : Bg;

        #pragma unroll
        for (int a = 0; a < 8; ++a)
            #pragma unroll
            for (int b = 0; b < 4; ++b) acc[a][b] = f32x4{0.f, 0.f, 0.f, 0.f};

        #pragma unroll
        for (int t = 0; t < 8; ++t) {
            const char* sb_ = sm + (size_t)(t & 1) * SLOT;
            char* ns_ = sm + (size_t)((t + 1) & 1) * SLOT;

            __syncthreads();   // vmcnt0+lgkm0 drain = slot handoff (R10)

            if ((t < 7) || hasNext) {
                const char* sA = (t < 7) ? Ag : An;
                const char* sB = (t < 7) ? Bg : Bn;
                stage8(sA, sB, (t < 7) ? (t + 1) * 128 : 0, ns_);
            }
            __builtin_amdgcn_sched_barrier(0);   // pin stage-issue first

            READ12(0);
            __builtin_amdgcn_s_setprio(1); MFMA32(); __builtin_amdgcn_s_setprio(0);
            READ12(1);
            __builtin_amdgcn_s_setprio(1); MFMA32(); __builtin_amdgcn_s_setprio(0);
        }

        // ---- epilogue (overlaps next tile's in-flight step-0 loads)
        const int s  = g >> 5;
        const int kb = (g >> 3) & 3;
        const int qb = g & 7;

        // copy loads issued first: latency hides under the LSE math below
        const float* csrc = (g < 784) ? (xp + (size_t)g * CHUNK)
                                      : (xq + (size_t)(g - 784) * CHUNK);
        float* cdst = outv + (size_t)g * CHUNK;
        f32x4 cbuf[12];
        #pragma unroll
        for (int i = 0; i < 12; ++i)
            cbuf[i] = *(const f32x4*)(csrc + tid * 4 + i * 2048);

        float q_m[4], q_s[4];
        #pragma unroll
        for (int b = 0; b < 4; ++b) {
            float m = -3.0e38f;
            #pragma unroll
            for (int a = 0; a < 8; ++a)
                #pragma unroll
                for (int r = 0; r < 4; ++r) m = fmaxf(m, acc[a][b][r]);
            float ss = 0.0f;
            #pragma unroll
            for (int a = 0; a < 8; ++a)
                #pragma unroll
                for (int r = 0; r < 4; ++r) ss += __expf(acc[a][b][r] - m);
            #pragma unroll
            for (int off = 16; off <= 32; off <<= 1) {
                float mo = __shfl_xor(m, off, 64);
                float so = __shfl_xor(ss, off, 64);
                float nm = fmaxf(m, mo);
                ss = ss * __expf(m - nm) + so * __expf(mo - nm);
                m = nm;
            }
            q_m[b] = m; q_s[b] = ss;
        }

        // diag (reads acc) before the copy stores
        if (kb == (qb & 3) && (wq >> 1) == wk) {
            float d = 0.0f;
            const bool lok = (((lane >> 2) & 3) == l4);
            if (wq & 1) {
                #pragma unroll
                for (int b = 0; b < 4; ++b)
                    #pragma unroll
                    for (int r = 0; r < 4; ++r)
                        if (lok && r == (lane & 3)) d += acc[4 + b][b][r];
            } else {
                #pragma unroll
                for (int b = 0; b < 4; ++b)
                    #pragma unroll
                    for (int r = 0; r < 4; ++r)
                        if (lok && r == (lane & 3)) d += acc[b][b][r];
            }
            #pragma unroll
            for (int off = 1; off < 64; off <<= 1) d += __shfl_xor(d, off, 64);
            if (lane == 0) atomicAdd(out, -d * SCALE);
        }

        // copy stores (retire during part-write + next-tile init slack)
        #pragma unroll
        for (int i = 0; i < 12; ++i)
            *(f32x4*)(cdst + tid * 4 + i * 2048) = cbuf[i];

        if (lane < 16) {
            const size_t rowb = (size_t)s * 2048 + (size_t)qb * 256 + wq * 64 + lane;
            #pragma unroll
            for (int b = 0; b < 4; ++b)
                part[(rowb + b * 16) * 8 + kb * 2 + wk] = make_float2(q_m[b], q_s[b]);
        }
    }
    #undef READ12
    #undef MFMA32
}

// merge the 8 per-(kb,wk) partials of each row -> lse, accumulate loss
__global__ __launch_bounds__(256) void reduce_kernel(
    const float2* __restrict__ part, float* __restrict__ out)
{
    const int row = blockIdx.x * 256 + threadIdx.x;   // 392*256 = 100352 rows
    const float2* p = part + (size_t)row * 8;
    float m = -3.0e38f;
    float2 q[8];
    #pragma unroll
    for (int i = 0; i < 8; ++i) { q[i] = p[i]; m = fmaxf(m, q[i].x); }
    float ssum = 0.0f;
    #pragma unroll
    for (int i = 0; i < 8; ++i) ssum += q[i].y * __expf(q[i].x - m);
    float v = m + __logf(ssum);
    #pragma unroll
    for (int off = 1; off < 64; off <<= 1) v += __shfl_xor(v, off, 64);
    __shared__ float red[4];
    const int lane = threadIdx.x & 63, w = threadIdx.x >> 6;
    if (lane == 0) red[w] = v;
    __syncthreads();
    if (threadIdx.x == 0)
        atomicAdd(out, (red[0] + red[1] + red[2] + red[3]) * SCALE);
}

extern "C" void kernel_launch(void* const* d_in, const int* in_sizes, int n_in,
                              void* d_out, int out_size, void* d_ws, size_t ws_size,
                              hipStream_t stream)
{
    (void)in_sizes; (void)n_in; (void)out_size; (void)ws_size;
    const float* f  = (const float*)d_in[0];
    const float* x  = (const float*)d_in[1];
    const float* xp = (const float*)d_in[2];
    const float* mt = (const float*)d_in[3];
    const float* mp = (const float*)d_in[4];
    const float* ct = (const float*)d_in[5];
    const float* cp = (const float*)d_in[6];
    float* out = (float*)d_out;

    char* ws = (char*)d_ws;
    const size_t packBytes = (size_t)SDIM * NDIM * DDIM * 2;   // 51.4 MB
    __hip_bfloat16* Km = (__hip_bfloat16*)ws;
    __hip_bfloat16* Qm = (__hip_bfloat16*)(ws + packBytes);
    __hip_bfloat16* Fm = (__hip_bfloat16*)(ws + 2 * packBytes);
    float2* part = (float2*)(ws + 2 * packBytes + (size_t)NDIM * DDIM * 2);

    pack_kernel<<<NDIM, 512, 0, stream>>>(xp, mp, cp, Km);
    pack_kernel<<<NDIM, 512, 0, stream>>>(x,  mt, ct, Qm);
    fpack_kernel<<<(NDIM * DDIM + 255) / 256, 256, 0, stream>>>(f, Fm, NDIM * DDIM, out);

    loss_kernel<<<256, 512, 2 * SLOT, stream>>>(Fm, Km, Qm, xp, x, out + 1, part, out);
    reduce_kernel<<<392, 256, 0, stream>>>(part, out);
}